// Round 3
// baseline (497.801 us; speedup 1.0000x reference)
//
#include <hip/hip_runtime.h>

#define NPROJ 180
#define DH 192
#define DW 384
#define VN 96
#define ZPER 4

// Block = 256 threads: 32 x-lanes x 8 y, one z-chunk of ZPER=4, one batch.
// The 4 waves of a block share ~the same detector footprint per projection
// (du/dy<=1.6px, dv/dy<=0.15px) -> cross-wave L1 line reuse on the same CU.
// All sample addresses are int32 offsets from a uniform base (SGPR base +
// VGPR offset addressing; +1/+DW become instruction immediates).
// (t00,t01)/(t10,t11) pairs load as single dwordx2 (gfx950 global loads
// support 4B-aligned float2).
__global__ __launch_bounds__(256) void cone_bp(
    const float* __restrict__ sino,   // [B, P, H, W]
    const float* __restrict__ mats,   // [P, 3, 4]
    float* __restrict__ out)          // [B, Z, Y, X]
{
    const int tid = threadIdx.x;
    const int x = blockIdx.x * 32 + (tid & 31);
    const int y = blockIdx.y * 8 + (tid >> 5);
    const int zc = blockIdx.z % (VN / ZPER);
    const int b  = blockIdx.z / (VN / ZPER);

    const float xw = (float)x - 47.5f;
    const float yw = (float)y - 47.5f;
    const float zw0 = (float)(zc * ZPER) - 47.5f;

    float acc[ZPER];
#pragma unroll
    for (int k = 0; k < ZPER; ++k) acc[k] = 0.0f;

    const float4* __restrict__ M = (const float4*)mats;
    const float* __restrict__ base = sino + (size_t)b * NPROJ * DH * DW;

    for (int p = 0; p < NPROJ; ++p) {
        float4 r0 = M[p * 3 + 0];
        float4 r1 = M[p * 3 + 1];
        float4 r2 = M[p * 3 + 2];
        // z-independent pieces (P02 = P22 = 0 exactly for this geometry)
        float un  = fmaf(r0.x, xw, fmaf(r0.y, yw, r0.w));
        float vn0 = fmaf(r1.x, xw, fmaf(r1.y, yw, r1.w));
        float w   = fmaf(r2.x, xw, fmaf(r2.y, yw, r2.w));
        float rw  = __builtin_amdgcn_rcpf(w);   // ~1 ulp; error << threshold
        float u   = un * rw;
        float iw2 = rw * rw;                    // FDK 1/w^2 weight
        float uf  = floorf(u);
        float fu  = u - uf;
        float gu  = 1.0f - fu;
        int   u0  = (int)uf;
        // geometry guarantees u0 in [73,309], v0 in [12,179] — no bounds checks
        int offp = p * (DH * DW) + u0;          // int32 offsets from uniform base
        float vbase = fmaf(r1.z, zw0, vn0) * rw;
        float dv    = r1.z * rw;                // v is linear in z

#pragma unroll
        for (int k = 0; k < ZPER; ++k) {
            float v  = fmaf(dv, (float)k, vbase);
            float vf = floorf(v);
            float fv = v - vf;
            int   vi = (int)vf;
            int  off = offp + vi * DW;
            float2 t0 = *(const float2*)(base + off);        // (t00, t01)
            float2 t1 = *(const float2*)(base + off + DW);   // (t10, t11)
            float top = fmaf(t0.y, fu, t0.x * gu);
            float bot = fmaf(t1.y, fu, t1.x * gu);
            float bil = fmaf(bot, fv, top * (1.0f - fv));
            acc[k] = fmaf(bil, iw2, acc[k]);
        }
    }

    const int zbase = zc * ZPER;
#pragma unroll
    for (int k = 0; k < ZPER; ++k) {
        out[(((size_t)(b * VN + zbase + k)) * VN + y) * VN + x] = acc[k];
    }
}

extern "C" void kernel_launch(void* const* d_in, const int* in_sizes, int n_in,
                              void* d_out, int out_size, void* d_ws, size_t ws_size,
                              hipStream_t stream) {
    const float* sino = (const float*)d_in[0];   // [2,180,192,384,1] fp32
    const float* mats = (const float*)d_in[1];   // [180,3,4] fp32
    float* out = (float*)d_out;                  // [2,96,96,96,1] fp32

    // grid: 3 x-tiles, 12 y-tiles, 24 z-chunks x 2 batches = 1728 blocks of 256
    dim3 grid(VN / 32, VN / 8, (VN / ZPER) * 2), block(256);
    hipLaunchKernelGGL(cone_bp, grid, block, 0, stream, sino, mats, out);
}

// Round 4
// 392.168 us; speedup vs baseline: 1.2694x; 1.2694x over previous
//
#include <hip/hip_runtime.h>

#define NPROJ 180
#define DH 192
#define DW 384
#define VN 96
#define ZPER 4
#define TILE_U 64
#define TILE_V 14

// Block = 256 threads: 32 x-lanes x 8 y, one z-chunk of ZPER=4, one batch.
// Per projection, the block's detector footprint is provably inside a
// 64x14 px window centered on the block-center projection:
//   |u - uc| <= 29.0  (1.7575*sqrt((15.5+3.5*g)^2+(3.5+15.5*g)^2), g=0.08)
//   |v - vc| <= 4.6   (1.944 w-variation + 1.5*1.7575 z-extent)
// and u in [73,310], v in [12,180] keeps the tile inside the detector.
// Stage the tile in LDS (coalesced float2 global loads), then bilinear
// from LDS via ds_read2_b32 pairs — removes the scattered-gather load on
// the L1/TCP pipe that pinned rounds 1-3 at ~390us.
__global__ __launch_bounds__(256) void cone_bp(
    const float* __restrict__ sino,   // [B, P, H, W]
    const float* __restrict__ mats,   // [P, 3, 4]
    float* __restrict__ out)          // [B, Z, Y, X]
{
    __shared__ float tile[TILE_V * TILE_U];

    const int tid = threadIdx.x;
    const int x = blockIdx.x * 32 + (tid & 31);
    const int y = blockIdx.y * 8 + (tid >> 5);
    const int zc = blockIdx.z % (VN / ZPER);
    const int b  = blockIdx.z / (VN / ZPER);

    const float xw = (float)x - 47.5f;
    const float yw = (float)y - 47.5f;
    const float zw0 = (float)(zc * ZPER) - 47.5f;

    // block-center world coords (for tile anchoring)
    const float xwc = (float)(blockIdx.x * 32) - 32.0f;  // +15.5 - 47.5
    const float ywc = (float)(blockIdx.y * 8) - 44.0f;   // +3.5  - 47.5
    const float zwc = (float)(zc * ZPER) - 46.0f;        // +1.5  - 47.5

    float acc[ZPER];
#pragma unroll
    for (int k = 0; k < ZPER; ++k) acc[k] = 0.0f;

    const float4* __restrict__ M = (const float4*)mats;
    const float* __restrict__ base = sino + (size_t)b * NPROJ * DH * DW;

    for (int p = 0; p < NPROJ; ++p) {
        float4 r0 = M[p * 3 + 0];
        float4 r1 = M[p * 3 + 1];
        float4 r2 = M[p * 3 + 2];

        // ---- tile anchor from block-center projection ----
        float unc = fmaf(r0.x, xwc, fmaf(r0.y, ywc, r0.w));
        float vnc = fmaf(r1.x, xwc, fmaf(r1.y, ywc, fmaf(r1.z, zwc, r1.w)));
        float wc  = fmaf(r2.x, xwc, fmaf(r2.y, ywc, r2.w));
        float rwc = __builtin_amdgcn_rcpf(wc);
        int iu0 = (int)floorf(unc * rwc) - (TILE_U / 2 - 1);  // -31
        int iv0 = (int)floorf(vnc * rwc) - 6;

        __syncthreads();  // previous projection's sampling done

        // ---- stage 64x14 tile: 448 float2, coalesced ----
        {
            const float* __restrict__ pimg =
                base + p * (DH * DW) + iv0 * DW + iu0;
            int r = tid >> 5;
            int c = (tid & 31) << 1;
            *(float2*)&tile[(r << 6) + c] = *(const float2*)(pimg + r * DW + c);
            if (tid < 192) {
                int r2i = (tid + 256) >> 5;
                *(float2*)&tile[(r2i << 6) + c] =
                    *(const float2*)(pimg + r2i * DW + c);
            }
        }
        __syncthreads();

        // ---- per-lane, z-invariant pieces (P02 = P22 = 0) ----
        float un  = fmaf(r0.x, xw, fmaf(r0.y, yw, r0.w));
        float vn0 = fmaf(r1.x, xw, fmaf(r1.y, yw, r1.w));
        float w   = fmaf(r2.x, xw, fmaf(r2.y, yw, r2.w));
        float rw  = __builtin_amdgcn_rcpf(w);
        float iw2 = rw * rw;                     // FDK 1/w^2 weight
        float ul  = un * rw - (float)iu0;        // tile-local u (exact shift)
        float uf  = floorf(ul);
        float fu  = ul - uf;
        float gu  = 1.0f - fu;
        int   u0l = (int)uf;
        float vb  = fmaf(r1.z, zw0, vn0) * rw - (float)iv0;  // tile-local v base
        float dv  = r1.z * rw;

#pragma unroll
        for (int k = 0; k < ZPER; ++k) {
            float v  = fmaf(dv, (float)k, vb);
            float vf = floorf(v);
            float fv = v - vf;
            int   o  = ((int)vf << 6) + u0l;
            float t00 = tile[o];
            float t01 = tile[o + 1];
            float t10 = tile[o + TILE_U];
            float t11 = tile[o + TILE_U + 1];
            float top = fmaf(t01, fu, t00 * gu);
            float bot = fmaf(t11, fu, t10 * gu);
            float bil = fmaf(bot, fv, top * (1.0f - fv));
            acc[k] = fmaf(bil, iw2, acc[k]);
        }
    }

    const int zbase = zc * ZPER;
#pragma unroll
    for (int k = 0; k < ZPER; ++k) {
        out[(((size_t)(b * VN + zbase + k)) * VN + y) * VN + x] = acc[k];
    }
}

extern "C" void kernel_launch(void* const* d_in, const int* in_sizes, int n_in,
                              void* d_out, int out_size, void* d_ws, size_t ws_size,
                              hipStream_t stream) {
    const float* sino = (const float*)d_in[0];   // [2,180,192,384,1] fp32
    const float* mats = (const float*)d_in[1];   // [180,3,4] fp32
    float* out = (float*)d_out;                  // [2,96,96,96,1] fp32

    // grid: 3 x-tiles, 12 y-tiles, 24 z-chunks x 2 batches = 1728 blocks of 256
    dim3 grid(VN / 32, VN / 8, (VN / ZPER) * 2), block(256);
    hipLaunchKernelGGL(cone_bp, grid, block, 0, stream, sino, mats, out);
}

// Round 5
// 384.883 us; speedup vs baseline: 1.2934x; 1.0189x over previous
//
#include <hip/hip_runtime.h>

#define NPROJ 180
#define DH 192
#define DW 384
#define VN 96
#define ZPER 4
#define TILE_U 64
#define TILE_V 14

typedef float v2f __attribute__((ext_vector_type(2)));

// Block = 256 threads: 32 x-lanes x 8 y, one z-chunk of ZPER=4, one batch.
// Footprint per projection (proved r4): |u-uc|<=29, |v-vc|<=4.6 -> 64x14 tile;
// u0l in [2,60], vi in [1,11]; global window [iu0, iu0+64] stays in-detector.
//
// r5 redesign:
//  - tile entry c holds the PAIR (img[c], img[c+1]) as float2 -> the 4 bilinear
//    taps are tile2[o] and tile2[o+64]: one ds_read2_b64 per sample (was 2x
//    ds_read2_b32) -> LDS instrs and conflicts halve.
//  - packed epilogue: C = A*gv + B*fv -> v_pk_fma_f32 on the loaded pairs.
//  - double-buffered staging: prefetch p+1 into regs before sampling p,
//    ds_write after -> 1 barrier/proj (was 2) and global latency overlapped.
__global__ __launch_bounds__(256) void cone_bp(
    const float* __restrict__ sino,   // [B, P, H, W]
    const float* __restrict__ mats,   // [P, 3, 4]
    float* __restrict__ out)          // [B, Z, Y, X]
{
    __shared__ v2f tile2[2][TILE_V * TILE_U];   // 2 x 7 KB

    const int tid = threadIdx.x;
    const int x = blockIdx.x * 32 + (tid & 31);
    const int y = blockIdx.y * 8 + (tid >> 5);
    const int zc = blockIdx.z % (VN / ZPER);
    const int b  = blockIdx.z / (VN / ZPER);

    const float xw = (float)x - 47.5f;
    const float yw = (float)y - 47.5f;
    const float zw0 = (float)(zc * ZPER) - 47.5f;

    // block-center world coords (tile anchoring)
    const float xwc = (float)(blockIdx.x * 32) - 32.0f;
    const float ywc = (float)(blockIdx.y * 8) - 44.0f;
    const float zwc = (float)(zc * ZPER) - 46.0f;

    const float4* __restrict__ M = (const float4*)mats;
    const float* __restrict__ base = sino + (size_t)b * NPROJ * DH * DW;

    // staging lane map: 64 cols x 4 row-groups; rows r, r+4, r+8 (+12 if r<2)
    const int sc = tid & 63;
    const int sr = tid >> 6;

#define ANCHOR(P, IU, IV)                                                   \
    {                                                                       \
        float4 a0 = M[(P) * 3 + 0];                                         \
        float4 a1 = M[(P) * 3 + 1];                                         \
        float4 a2 = M[(P) * 3 + 2];                                         \
        float unc = fmaf(a0.x, xwc, fmaf(a0.y, ywc, a0.w));                 \
        float vnc = fmaf(a1.x, xwc, fmaf(a1.y, ywc, fmaf(a1.z, zwc, a1.w)));\
        float wc  = fmaf(a2.x, xwc, fmaf(a2.y, ywc, a2.w));                 \
        float rwc = __builtin_amdgcn_rcpf(wc);                              \
        IU = (int)floorf(unc * rwc) - (TILE_U / 2 - 1);                     \
        IV = (int)floorf(vnc * rwc) - 6;                                    \
    }

    // ---- prologue: stage p=0 into buffer 0 ----
    {
        int iu0, iv0;
        ANCHOR(0, iu0, iv0)
        const float* __restrict__ pimg = base + iv0 * DW + iu0;
        v2f g0 = *(const v2f*)(pimg + sr * DW + sc);
        v2f g1 = *(const v2f*)(pimg + (sr + 4) * DW + sc);
        v2f g2 = *(const v2f*)(pimg + (sr + 8) * DW + sc);
        tile2[0][((sr) << 6) + sc] = g0;
        tile2[0][((sr + 4) << 6) + sc] = g1;
        tile2[0][((sr + 8) << 6) + sc] = g2;
        if (sr < 2) {
            v2f g3 = *(const v2f*)(pimg + (sr + 12) * DW + sc);
            tile2[0][((sr + 12) << 6) + sc] = g3;
        }
    }

    float acc[ZPER];
#pragma unroll
    for (int k = 0; k < ZPER; ++k) acc[k] = 0.0f;

    for (int p = 0; p < NPROJ; ++p) {
        __syncthreads();   // buf[p&1] staged; prev sampling of buf[(p+1)&1] done

        // ---- prefetch p+1 window into registers (no LDS yet) ----
        v2f g0, g1, g2, g3;
        const bool has_next = (p + 1 < NPROJ);
        if (has_next) {
            int niu0, niv0;
            ANCHOR(p + 1, niu0, niv0)
            const float* __restrict__ pimg =
                base + (p + 1) * (DH * DW) + niv0 * DW + niu0;
            g0 = *(const v2f*)(pimg + sr * DW + sc);
            g1 = *(const v2f*)(pimg + (sr + 4) * DW + sc);
            g2 = *(const v2f*)(pimg + (sr + 8) * DW + sc);
            if (sr < 2) g3 = *(const v2f*)(pimg + (sr + 12) * DW + sc);
        }

        // ---- sample projection p from buf[p&1] ----
        {
            float4 r0 = M[p * 3 + 0];
            float4 r1 = M[p * 3 + 1];
            float4 r2 = M[p * 3 + 2];
            int iu0, iv0;
            ANCHOR(p, iu0, iv0)
            float un  = fmaf(r0.x, xw, fmaf(r0.y, yw, r0.w));
            float vn0 = fmaf(r1.x, xw, fmaf(r1.y, yw, r1.w));
            float w   = fmaf(r2.x, xw, fmaf(r2.y, yw, r2.w));
            float rw  = __builtin_amdgcn_rcpf(w);
            float iw2 = rw * rw;                       // FDK 1/w^2
            float ul  = un * rw - (float)iu0;          // tile-local u
            float uf  = floorf(ul);
            float fu  = ul - uf;
            float gu  = 1.0f - fu;
            int   u0l = (int)uf;
            float vb  = fmaf(r1.z, zw0, vn0) * rw - (float)iv0;
            float dv  = r1.z * rw;

            const v2f* __restrict__ tb = tile2[p & 1];
#pragma unroll
            for (int k = 0; k < ZPER; ++k) {
                float v  = fmaf(dv, (float)k, vb);
                float vf = floorf(v);
                float fv = v - vf;
                int   o  = ((int)vf << 6) + u0l;
                v2f A = tb[o];         // (t00, t01)
                v2f B = tb[o + 64];    // (t10, t11)  -> one ds_read2_b64
                v2f C = A * (1.0f - fv) + B * fv;      // v_pk_mul + v_pk_fma
                float bil = fmaf(C.y, fu, C.x * gu);
                acc[k] = fmaf(bil, iw2, acc[k]);
            }
        }

        // ---- commit prefetched tile to buf[(p+1)&1] ----
        if (has_next) {
            v2f* __restrict__ dst = tile2[(p + 1) & 1];
            dst[((sr) << 6) + sc] = g0;
            dst[((sr + 4) << 6) + sc] = g1;
            dst[((sr + 8) << 6) + sc] = g2;
            if (sr < 2) dst[((sr + 12) << 6) + sc] = g3;
        }
    }

    const int zbase = zc * ZPER;
#pragma unroll
    for (int k = 0; k < ZPER; ++k) {
        out[(((size_t)(b * VN + zbase + k)) * VN + y) * VN + x] = acc[k];
    }
#undef ANCHOR
}

extern "C" void kernel_launch(void* const* d_in, const int* in_sizes, int n_in,
                              void* d_out, int out_size, void* d_ws, size_t ws_size,
                              hipStream_t stream) {
    const float* sino = (const float*)d_in[0];   // [2,180,192,384,1] fp32
    const float* mats = (const float*)d_in[1];   // [180,3,4] fp32
    float* out = (float*)d_out;                  // [2,96,96,96,1] fp32

    dim3 grid(VN / 32, VN / 8, (VN / ZPER) * 2), block(256);
    hipLaunchKernelGGL(cone_bp, grid, block, 0, stream, sino, mats, out);
}

// Round 6
// 367.913 us; speedup vs baseline: 1.3530x; 1.0461x over previous
//
#include <hip/hip_runtime.h>

#define NPROJ 180
#define DH 192
#define DW 384
#define VN 96
#define ZPER 8
#define TILE_U 64
#define TILE_V 20

typedef float v2f __attribute__((ext_vector_type(2)));

// Block = 256 threads: 32 x-lanes x 8 y, one z-chunk of ZPER=8, one batch.
// 864 blocks. Footprint per projection (re-derived for z half-extent 3.5):
//   |u-uc| <= 29.0  (z-independent, as r4)        -> 64-wide tile (pairs)
//   |v-vc| <= 1.944 + 3.5*1.7575 = 8.1            -> 20 rows, iv0=floor(vc)-9
// Tile entry c = pair (img[c], img[c+1]) -> bilinear = one ds_read2_b64.
// r6: ZPER 8 amortizes per-projection setup/anchor/staging/barrier over 8
// samples; anchors computed once and carried; readfirstlane scalarizes all
// staging address math; inner loop is 9 VALU/sample with phase-split LDS
// reads for MLP (3456 waves = 3.4/SIMD is enough for 120cy LDS latency).
__global__ __launch_bounds__(256) void cone_bp(
    const float* __restrict__ sino,   // [B, P, H, W]
    const float* __restrict__ mats,   // [P, 3, 4]
    float* __restrict__ out)          // [B, Z, Y, X]
{
    __shared__ v2f tile2[2][TILE_V * TILE_U];   // 2 x 10 KB

    const int tid = threadIdx.x;
    const int x = blockIdx.x * 32 + (tid & 31);
    const int y = blockIdx.y * 8 + (tid >> 5);
    const int zc = blockIdx.z % (VN / ZPER);
    const int b  = blockIdx.z / (VN / ZPER);

    const float xw = (float)x - 47.5f;
    const float yw = (float)y - 47.5f;
    const float zw0 = (float)(zc * ZPER) - 47.5f;

    // block-center world coords (tile anchoring)
    const float xwc = (float)(blockIdx.x * 32) - 32.0f;   // +15.5 - 47.5
    const float ywc = (float)(blockIdx.y * 8) - 44.0f;    // +3.5  - 47.5
    const float zwc = (float)(zc * ZPER) - 44.0f;         // +3.5  - 47.5

    const float4* __restrict__ M = (const float4*)mats;
    const float* __restrict__ base = sino + (size_t)b * NPROJ * DH * DW;

    // staging lane map: 64 cols x 4 row-groups, 5 rows/thread (20 rows exact)
    const int sc = tid & 63;
    const int sr = tid >> 6;
    const int lane_off = sr * DW + sc;            // loop-invariant VGPR
    const int lds_off = (sr << 6) + sc;           // tile2 element index

#define ANCHOR(P, IU, IV)                                                   \
    {                                                                       \
        float4 a0 = M[(P) * 3 + 0];                                         \
        float4 a1 = M[(P) * 3 + 1];                                         \
        float4 a2 = M[(P) * 3 + 2];                                         \
        float unc = fmaf(a0.x, xwc, fmaf(a0.y, ywc, a0.w));                 \
        float vnc = fmaf(a1.x, xwc, fmaf(a1.y, ywc, fmaf(a1.z, zwc, a1.w)));\
        float wc  = fmaf(a2.x, xwc, fmaf(a2.y, ywc, a2.w));                 \
        float rwc = __builtin_amdgcn_rcpf(wc);                              \
        IU = __builtin_amdgcn_readfirstlane((int)floorf(unc * rwc) - 31);   \
        IV = __builtin_amdgcn_readfirstlane((int)floorf(vnc * rwc) - 9);    \
    }

    // ---- prologue: anchor + stage p=0 into buffer 0 ----
    int siu, siv;                                 // anchor of projection p
    ANCHOR(0, siu, siv)
    {
        const float* __restrict__ pimg = base + siv * DW + siu;
#pragma unroll
        for (int r = 0; r < 5; ++r)
            tile2[0][lds_off + (r << 8)] =
                *(const v2f*)(pimg + lane_off + r * 4 * DW);
    }

    float acc[ZPER];
#pragma unroll
    for (int k = 0; k < ZPER; ++k) acc[k] = 0.0f;

    for (int p = 0; p < NPROJ; ++p) {
        __syncthreads();   // buf[p&1] staged; prev sampling of other buf done

        // ---- prefetch p+1 window into registers ----
        v2f g[5];
        int niu = siu, niv = siv;
        const bool has_next = (p + 1 < NPROJ);
        if (has_next) {
            ANCHOR(p + 1, niu, niv)
            const float* __restrict__ pimg =
                base + (p + 1) * (DH * DW) + niv * DW + niu;
#pragma unroll
            for (int r = 0; r < 5; ++r)
                g[r] = *(const v2f*)(pimg + lane_off + r * 4 * DW);
        }

        // ---- sample projection p from buf[p&1] ----
        {
            float4 r0 = M[p * 3 + 0];
            float4 r1 = M[p * 3 + 1];
            float4 r2 = M[p * 3 + 2];
            float un  = fmaf(r0.x, xw, fmaf(r0.y, yw, r0.w));
            float vn0 = fmaf(r1.x, xw, fmaf(r1.y, yw, r1.w));
            float w   = fmaf(r2.x, xw, fmaf(r2.y, yw, r2.w));
            float rw  = __builtin_amdgcn_rcpf(w);
            float iw2 = rw * rw;                         // FDK 1/w^2
            float ul  = fmaf(un, rw, -(float)siu);       // tile-local u
            float uf  = floorf(ul);
            float fu  = ul - uf;
            int   u0l = (int)uf;
            float vb  = fmaf(fmaf(r1.z, zw0, vn0), rw, -(float)siv);
            float dv  = r1.z * rw;

            const v2f* __restrict__ tb = tile2[p & 1];

            // phase 1: offsets + fv
            int   o[ZPER];
            float fv[ZPER];
#pragma unroll
            for (int k = 0; k < ZPER; ++k) {
                float v  = fmaf(dv, (float)k, vb);
                float vf = floorf(v);
                fv[k] = v - vf;
                o[k] = ((int)vf << 6) + u0l;
            }
            // phase 2: all LDS reads (ds_read2_b64 each, batched for MLP)
            v2f A[ZPER], B[ZPER];
#pragma unroll
            for (int k = 0; k < ZPER; ++k) {
                A[k] = tb[o[k]];
                B[k] = tb[o[k] + TILE_U];
            }
            // phase 3: lerp + accumulate
#pragma unroll
            for (int k = 0; k < ZPER; ++k) {
                v2f C = A[k] + (B[k] - A[k]) * fv[k];    // pk_add + pk_fma
                float h = fmaf(C.y - C.x, fu, C.x);
                acc[k] = fmaf(h, iw2, acc[k]);
            }
        }

        // ---- commit prefetched tile to buf[(p+1)&1] ----
        if (has_next) {
            v2f* __restrict__ dst = tile2[(p + 1) & 1];
#pragma unroll
            for (int r = 0; r < 5; ++r)
                dst[lds_off + (r << 8)] = g[r];
        }
        siu = niu; siv = niv;
    }

    const int zbase = zc * ZPER;
#pragma unroll
    for (int k = 0; k < ZPER; ++k) {
        out[(((size_t)(b * VN + zbase + k)) * VN + y) * VN + x] = acc[k];
    }
#undef ANCHOR
}

extern "C" void kernel_launch(void* const* d_in, const int* in_sizes, int n_in,
                              void* d_out, int out_size, void* d_ws, size_t ws_size,
                              hipStream_t stream) {
    const float* sino = (const float*)d_in[0];   // [2,180,192,384,1] fp32
    const float* mats = (const float*)d_in[1];   // [180,3,4] fp32
    float* out = (float*)d_out;                  // [2,96,96,96,1] fp32

    // grid: 3 x-tiles, 12 y-tiles, 12 z-chunks x 2 batches = 864 blocks of 256
    dim3 grid(VN / 32, VN / 8, (VN / ZPER) * 2), block(256);
    hipLaunchKernelGGL(cone_bp, grid, block, 0, stream, sino, mats, out);
}

// Round 7
// 345.335 us; speedup vs baseline: 1.4415x; 1.0654x over previous
//
#include <hip/hip_runtime.h>

#define NPROJ 180
#define DH 192
#define DW 384
#define VN 96
#define ZPER 4
#define TILE_U 64
#define TILE_V 14
#define TSIZE (TILE_U * TILE_V)     // 896 pairs per batch tile
#define PSTRIDE (DH * DW)
#define BSTRIDE (NPROJ * DH * DW)

typedef float v2f __attribute__((ext_vector_type(2)));

// Block = 256 threads covering 32x x 8y, ZPER=4 z, BOTH batches (geometry is
// batch-independent: anchors, per-proj setup, and per-sample v/fv/o are
// computed once and reused for 2 samples). Grid = 3 x 12 x 24 = 864 blocks.
//
// Footprint (proved r4, unchanged): 64x14 pair-tile per batch; u0l in [2,60],
// vi in [1,11]; global window stays in-detector.
//
// r7 changes vs r6:
//  - merged batches: per-proj VALU amortized over 8 samples, phase-1 shared.
//  - 8x x 8y lane map per wave: u-span <=16px -> pair-bank aliasing ~2-way
//    (free per m136) instead of ~4-way at 32x-lane span ~50px.
//  - staging fully linearized: 1792 pairs = 7*256 -> per-thread global vaddr
//    and LDS write addresses are loop-invariant; per-proj address update is
//    scalar-only (readfirstlane'd anchors).
__global__ __launch_bounds__(256) void cone_bp(
    const float* __restrict__ sino,   // [B, P, H, W]
    const float* __restrict__ mats,   // [P, 3, 4]
    float* __restrict__ out)          // [B, Z, Y, X]
{
    __shared__ v2f tile2[2][2 * TSIZE];   // [buf][batch*TSIZE + row*64 + col]

    const int tid = threadIdx.x;
    // wave-local 8x x 8y map: x low 3 bits from tid[0:2], x high from tid[6:7]
    const int x = blockIdx.x * 32 + ((tid & 7) | ((tid >> 6) << 3));
    const int y = blockIdx.y * 8 + ((tid >> 3) & 7);
    const int zc = blockIdx.z;

    const float xw = (float)x - 47.5f;
    const float yw = (float)y - 47.5f;
    const float zw0 = (float)(zc * ZPER) - 47.5f;

    // block-center world coords (tile anchoring)
    const float xwc = (float)(blockIdx.x * 32) - 32.0f;   // +15.5 - 47.5
    const float ywc = (float)(blockIdx.y * 8) - 44.0f;    // +3.5  - 47.5
    const float zwc = (float)(zc * ZPER) - 46.0f;         // +1.5  - 47.5

    const float4* __restrict__ M = (const float4*)mats;

    // ---- staging map: linear index li = tid + 256k, k<7 covers 1792 pairs ----
    int V[7];           // loop-invariant global float-offsets (incl. batch)
#pragma unroll
    for (int k = 0; k < 7; ++k) {
        int li = tid + 256 * k;
        int bb = (li >= TSIZE) ? 1 : 0;
        int rem = li - bb * TSIZE;
        V[k] = bb * BSTRIDE + (rem >> 6) * DW + (rem & 63);
    }

#define ANCHOR(P, IU, IV)                                                   \
    {                                                                       \
        float4 a0 = M[(P) * 3 + 0];                                         \
        float4 a1 = M[(P) * 3 + 1];                                         \
        float4 a2 = M[(P) * 3 + 2];                                         \
        float unc = fmaf(a0.x, xwc, fmaf(a0.y, ywc, a0.w));                 \
        float vnc = fmaf(a1.x, xwc, fmaf(a1.y, ywc, fmaf(a1.z, zwc, a1.w)));\
        float wc  = fmaf(a2.x, xwc, fmaf(a2.y, ywc, a2.w));                 \
        float rwc = __builtin_amdgcn_rcpf(wc);                              \
        IU = __builtin_amdgcn_readfirstlane((int)floorf(unc * rwc) - 31);   \
        IV = __builtin_amdgcn_readfirstlane((int)floorf(vnc * rwc) - 6);    \
    }

    // ---- prologue: anchor + stage p=0 into buffer 0 ----
    int siu, siv;
    ANCHOR(0, siu, siv)
    {
        const float* __restrict__ ps = sino + siv * DW + siu;  // uniform
#pragma unroll
        for (int k = 0; k < 7; ++k)
            tile2[0][tid + 256 * k] = *(const v2f*)(ps + V[k]);
    }

    float acc0[ZPER], acc1[ZPER];
#pragma unroll
    for (int k = 0; k < ZPER; ++k) { acc0[k] = 0.0f; acc1[k] = 0.0f; }

    for (int p = 0; p < NPROJ; ++p) {
        __syncthreads();   // buf[p&1] staged; prev sampling of other buf done

        // ---- prefetch p+1 window into registers ----
        v2f g[7];
        int niu = siu, niv = siv;
        const bool has_next = (p + 1 < NPROJ);
        if (has_next) {
            ANCHOR(p + 1, niu, niv)
            const float* __restrict__ ps =
                sino + (p + 1) * PSTRIDE + niv * DW + niu;     // uniform
#pragma unroll
            for (int k = 0; k < 7; ++k)
                g[k] = *(const v2f*)(ps + V[k]);
        }

        // ---- sample projection p (both batches) from buf[p&1] ----
        {
            float4 r0 = M[p * 3 + 0];
            float4 r1 = M[p * 3 + 1];
            float4 r2 = M[p * 3 + 2];
            float un  = fmaf(r0.x, xw, fmaf(r0.y, yw, r0.w));
            float vn0 = fmaf(r1.x, xw, fmaf(r1.y, yw, r1.w));
            float w   = fmaf(r2.x, xw, fmaf(r2.y, yw, r2.w));
            float rw  = __builtin_amdgcn_rcpf(w);
            float iw2 = rw * rw;                         // FDK 1/w^2
            float ul  = fmaf(un, rw, -(float)siu);       // tile-local u
            float uf  = floorf(ul);
            float fu  = ul - uf;
            int   u0l = (int)uf;
            float vb  = fmaf(fmaf(r1.z, zw0, vn0), rw, -(float)siv);
            float dv  = r1.z * rw;

            const v2f* __restrict__ tb = tile2[p & 1];

            // phase 1: shared offsets + fv (once for both batches)
            int   o[ZPER];
            float fv[ZPER];
#pragma unroll
            for (int k = 0; k < ZPER; ++k) {
                float v  = fmaf(dv, (float)k, vb);
                float vf = floorf(v);
                fv[k] = v - vf;
                o[k] = ((int)vf << 6) + u0l;
            }
            // phase 2: all LDS reads (ds_read2_b64 each; 8 in flight)
            v2f A0[ZPER], B0[ZPER], A1[ZPER], B1[ZPER];
#pragma unroll
            for (int k = 0; k < ZPER; ++k) {
                A0[k] = tb[o[k]];
                B0[k] = tb[o[k] + TILE_U];
                A1[k] = tb[o[k] + TSIZE];
                B1[k] = tb[o[k] + TSIZE + TILE_U];
            }
            // phase 3: lerp + accumulate, both batches share fv/fu/iw2
#pragma unroll
            for (int k = 0; k < ZPER; ++k) {
                v2f C0 = A0[k] + (B0[k] - A0[k]) * fv[k];
                v2f C1 = A1[k] + (B1[k] - A1[k]) * fv[k];
                float h0 = fmaf(C0.y - C0.x, fu, C0.x);
                float h1 = fmaf(C1.y - C1.x, fu, C1.x);
                acc0[k] = fmaf(h0, iw2, acc0[k]);
                acc1[k] = fmaf(h1, iw2, acc1[k]);
            }
        }

        // ---- commit prefetched tile to buf[(p+1)&1] ----
        if (has_next) {
            v2f* __restrict__ dst = tile2[(p + 1) & 1];
#pragma unroll
            for (int k = 0; k < 7; ++k)
                dst[tid + 256 * k] = g[k];
        }
        siu = niu; siv = niv;
    }

    const int zbase = zc * ZPER;
#pragma unroll
    for (int k = 0; k < ZPER; ++k) {
        out[(((size_t)(zbase + k)) * VN + y) * VN + x] = acc0[k];
        out[(((size_t)(VN + zbase + k)) * VN + y) * VN + x] = acc1[k];
    }
#undef ANCHOR
}

extern "C" void kernel_launch(void* const* d_in, const int* in_sizes, int n_in,
                              void* d_out, int out_size, void* d_ws, size_t ws_size,
                              hipStream_t stream) {
    const float* sino = (const float*)d_in[0];   // [2,180,192,384,1] fp32
    const float* mats = (const float*)d_in[1];   // [180,3,4] fp32
    float* out = (float*)d_out;                  // [2,96,96,96,1] fp32

    // grid: 3 x-tiles, 12 y-tiles, 24 z-chunks (both batches per block)
    dim3 grid(VN / 32, VN / 8, VN / ZPER), block(256);
    hipLaunchKernelGGL(cone_bp, grid, block, 0, stream, sino, mats, out);
}